// Round 1
// baseline (319.233 us; speedup 1.0000x reference)
//
#include <hip/hip_runtime.h>
#include <cstdint>
#include <cstddef>

#define BATCH   8192
#define IN_DIM  2048
#define OUT_DIM 512
#define TREES   16
#define NI_     15
#define NCOL    256            // TREES * 16 (15 real nodes + 1 zero pad per tree)
#define KS      4              // K-split for GEMM1
#define KHALF   (IN_DIM/KS)    // 512
#define BK      32
#define BM1     64             // GEMM1 row tile
#define BM2     16             // finish-kernel row tile

__device__ __forceinline__ float f4c(const float4& v, int j) {
  return j == 0 ? v.x : j == 1 ? v.y : j == 2 ? v.z : v.w;
}

// ---------------- prep: Wr[k][t*16+n] = nw[t][k][n] (n<15), 0 pad ----------------
__global__ void kprepW(const float* __restrict__ nw, float* __restrict__ Wr) {
  int idx = blockIdx.x * blockDim.x + threadIdx.x;   // float4 index, < 131072
  int k   = idx >> 6;            // 0..2047
  int col = (idx & 63) * 4;      // 0..252 step 4
  int t   = col >> 4;
  int n   = col & 15;            // 0,4,8,12
  const float* src = nw + ((size_t)t * IN_DIM + k) * NI_ + n;
  float4 v;
  v.x = (n + 0 < NI_) ? src[0] : 0.f;
  v.y = (n + 1 < NI_) ? src[1] : 0.f;
  v.z = (n + 2 < NI_) ? src[2] : 0.f;
  v.w = (n + 3 < NI_) ? src[3] : 0.f;
  *(float4*)(Wr + (size_t)k * NCOL + col) = v;
}

// ---------------- prep: LWr[t*16+l][o] = lw[t][o][l] ----------------
__global__ void kprepL(const float* __restrict__ lw, float* __restrict__ LWr) {
  int idx = blockIdx.x * blockDim.x + threadIdx.x;   // float4 index, < 32768
  int kk  = idx >> 7;            // 0..255
  int o   = (idx & 127) * 4;
  int t   = kk >> 4;
  int l   = kk & 15;
  const float* src = lw + (size_t)t * OUT_DIM * 16 + l;  // lw[t][o][l]
  float4 v;
  v.x = src[(size_t)(o + 0) * 16];
  v.y = src[(size_t)(o + 1) * 16];
  v.z = src[(size_t)(o + 2) * 16];
  v.w = src[(size_t)(o + 3) * 16];
  *(float4*)(LWr + (size_t)kk * OUT_DIM + o) = v;
}

// ---------------- GEMM1: Apart[kh][b][c] = sum_{k in half} x[b][k] * Wr[k][c] ----------------
// 512 blocks = 128 row-tiles x 4 k-halves, 256 threads (4 waves).
// Wave w: rows 16w..16w+15; lane owns cols 4*lane..4*lane+3.
__global__ __launch_bounds__(256)
void k1(const float* __restrict__ x, const float* __restrict__ Wr,
        float* __restrict__ Apart) {
  __shared__ float Xs[BK][68];     // k-major, padded stride (16B-aligned rows, low write conflicts)
  __shared__ float Ws[BK][NCOL];

  const int tid  = threadIdx.x;
  const int lane = tid & 63;
  const int wv   = tid >> 6;
  const int rt   = blockIdx.x & 127;
  const int kh   = blockIdx.x >> 7;
  const int r0   = rt * BM1;
  const int kbase = kh * KHALF;
  const int xr = tid >> 3;         // 0..31
  const int xq = tid & 7;          // float4 slot in 32-float k-chunk

  float4 acc[16];
  #pragma unroll
  for (int i = 0; i < 16; i++) acc[i] = make_float4(0.f, 0.f, 0.f, 0.f);

  for (int ch = 0; ch < KHALF / BK; ++ch) {
    const int k0 = kbase + ch * BK;
    // ---- stage loads (issued before barrier; in flight across it) ----
    float4 xa = *(const float4*)(x + (size_t)(r0 + xr) * IN_DIM + k0 + 4 * xq);
    float4 xb = *(const float4*)(x + (size_t)(r0 + xr + 32) * IN_DIM + k0 + 4 * xq);
    float4 wbuf[8];
    #pragma unroll
    for (int i = 0; i < 8; i++)
      wbuf[i] = *(const float4*)(Wr + (size_t)k0 * NCOL + 4 * (tid + 256 * i));
    __syncthreads();               // previous iteration's LDS reads done
    Xs[4 * xq + 0][xr] = xa.x;  Xs[4 * xq + 1][xr] = xa.y;
    Xs[4 * xq + 2][xr] = xa.z;  Xs[4 * xq + 3][xr] = xa.w;
    Xs[4 * xq + 0][xr + 32] = xb.x;  Xs[4 * xq + 1][xr + 32] = xb.y;
    Xs[4 * xq + 2][xr + 32] = xb.z;  Xs[4 * xq + 3][xr + 32] = xb.w;
    #pragma unroll
    for (int i = 0; i < 8; i++) {
      int f = tid + 256 * i;       // linear float4 over [32][64]
      *(float4*)&Ws[f >> 6][(f & 63) * 4] = wbuf[i];
    }
    __syncthreads();
    // ---- compute: per k-step: 1 full-row b128 (W) + 4 broadcast f4 (X), 64 FMA/lane ----
    #pragma unroll 4
    for (int k = 0; k < BK; k++) {
      float4 w4 = *(const float4*)&Ws[k][4 * lane];
      #pragma unroll
      for (int q = 0; q < 4; q++) {
        float4 xq4 = *(const float4*)&Xs[k][16 * wv + 4 * q];
        #pragma unroll
        for (int j = 0; j < 4; j++) {
          float xv = f4c(xq4, j);
          float4& A = acc[4 * q + j];
          A.x = fmaf(xv, w4.x, A.x);
          A.y = fmaf(xv, w4.y, A.y);
          A.z = fmaf(xv, w4.z, A.z);
          A.w = fmaf(xv, w4.w, A.w);
        }
      }
    }
  }
  float* outp = Apart + ((size_t)kh * BATCH + r0 + 16 * wv) * NCOL + 4 * lane;
  #pragma unroll
  for (int j = 0; j < 16; j++)
    *(float4*)(outp + (size_t)j * NCOL) = acc[j];
}

// ---------------- finish: sum K-partials, gates, leaf probs, GEMM2 ----------------
// 512 blocks x 256 threads; BM2=16 rows per block.
__global__ __launch_bounds__(256)
void k2(const float* __restrict__ Apart, const float* __restrict__ LWr,
        float* __restrict__ out) {
  __shared__ float P[BM2][NCOL];   // 16 KB leaf-prob tile

  const int tid = threadIdx.x;
  const int r0  = blockIdx.x * BM2;

  // ---- gates: thread handles one (row, tree) pair ----
  const int row = tid >> 4;        // 0..15
  const int tr  = tid & 15;        // 0..15
  float av[16];
  #pragma unroll
  for (int m = 0; m < 16; m++) av[m] = 0.f;
  for (int h = 0; h < KS; ++h) {
    const float* ap = Apart + ((size_t)h * BATCH + r0 + row) * NCOL + tr * 16;
    #pragma unroll
    for (int q = 0; q < 4; q++) {
      float4 v = *(const float4*)(ap + 4 * q);
      av[4 * q + 0] += v.x;  av[4 * q + 1] += v.y;
      av[4 * q + 2] += v.z;  av[4 * q + 3] += v.w;
    }
  }
  float sg[15];
  #pragma unroll
  for (int m = 0; m < 15; m++) {
    float t = av[m] + 0.5f;                 // SMOOTH_STEP_PARAM = 1
    t = fminf(fmaxf(t, 0.f), 1.f);
    sg[m] = t * t * (3.f - 2.f * t);
  }
  float p[16];
  #pragma unroll
  for (int l = 0; l < 16; l++) {
    float pr = 1.f;
    int node = 0;
    #pragma unroll
    for (int L = 0; L < 4; L++) {
      int bit = (l >> (3 - L)) & 1;         // 0 = left (gate s), 1 = right (1-s)
      pr *= bit ? (1.f - sg[node]) : sg[node];
      node = 2 * node + 1 + bit;
    }
    p[l] = pr;
  }
  #pragma unroll
  for (int q = 0; q < 4; q++)
    *(float4*)&P[row][tr * 16 + 4 * q] =
        make_float4(p[4 * q], p[4 * q + 1], p[4 * q + 2], p[4 * q + 3]);
  __syncthreads();

  // ---- GEMM2: out[16][512] = P[16][256] * LWr[256][512] ----
  const int lane = tid & 63;
  const int wv   = tid >> 6;       // wave w: rows 4w..4w+3; lane: cols 8*lane..8*lane+7
  float4 acc[4][2];
  #pragma unroll
  for (int r = 0; r < 4; r++) {
    acc[r][0] = make_float4(0.f, 0.f, 0.f, 0.f);
    acc[r][1] = make_float4(0.f, 0.f, 0.f, 0.f);
  }
  for (int kk = 0; kk < NCOL; kk += 4) {
    float4 pv[4];
    #pragma unroll
    for (int r = 0; r < 4; r++)
      pv[r] = *(const float4*)&P[4 * wv + r][kk];   // broadcast reads
    #pragma unroll
    for (int kj = 0; kj < 4; kj++) {
      const float* wrow = LWr + (size_t)(kk + kj) * OUT_DIM + 8 * lane;
      float4 w0 = *(const float4*)(wrow);
      float4 w1 = *(const float4*)(wrow + 4);
      #pragma unroll
      for (int r = 0; r < 4; r++) {
        float pj = f4c(pv[r], kj);
        acc[r][0].x = fmaf(pj, w0.x, acc[r][0].x);
        acc[r][0].y = fmaf(pj, w0.y, acc[r][0].y);
        acc[r][0].z = fmaf(pj, w0.z, acc[r][0].z);
        acc[r][0].w = fmaf(pj, w0.w, acc[r][0].w);
        acc[r][1].x = fmaf(pj, w1.x, acc[r][1].x);
        acc[r][1].y = fmaf(pj, w1.y, acc[r][1].y);
        acc[r][1].z = fmaf(pj, w1.z, acc[r][1].z);
        acc[r][1].w = fmaf(pj, w1.w, acc[r][1].w);
      }
    }
  }
  #pragma unroll
  for (int r = 0; r < 4; r++) {
    float* op = out + (size_t)(r0 + 4 * wv + r) * OUT_DIM + 8 * lane;
    *(float4*)(op)     = acc[r][0];
    *(float4*)(op + 4) = acc[r][1];
  }
}

extern "C" void kernel_launch(void* const* d_in, const int* in_sizes, int n_in,
                              void* d_out, int out_size, void* d_ws, size_t ws_size,
                              hipStream_t stream) {
  const float* x  = (const float*)d_in[0];
  const float* nw = (const float*)d_in[1];
  const float* lw = (const float*)d_in[2];
  float* out = (float*)d_out;

  char* ws = (char*)d_ws;
  const size_t wr_bytes  = (size_t)IN_DIM * NCOL * sizeof(float);    // 2 MB
  const size_t lwr_bytes = (size_t)NCOL * OUT_DIM * sizeof(float);   // 512 KB
  float* Wr    = (float*)(ws);
  float* LWr   = (float*)(ws + wr_bytes);
  float* Apart = (float*)(ws + wr_bytes + lwr_bytes);                // 32 MB

  hipLaunchKernelGGL(kprepW, dim3(IN_DIM * NCOL / 4 / 256), dim3(256), 0, stream, nw, Wr);
  hipLaunchKernelGGL(kprepL, dim3(NCOL * OUT_DIM / 4 / 256), dim3(256), 0, stream, lw, LWr);
  hipLaunchKernelGGL(k1, dim3((BATCH / BM1) * KS), dim3(256), 0, stream, x, Wr, Apart);
  hipLaunchKernelGGL(k2, dim3(BATCH / BM2), dim3(256), 0, stream, Apart, LWr, out);
}

// Round 3
// 137.141 us; speedup vs baseline: 2.3278x; 2.3278x over previous
//
#include <hip/hip_runtime.h>
#include <cstdint>
#include <cstddef>

typedef __fp16 half8 __attribute__((ext_vector_type(8)));
typedef float  f32x4 __attribute__((ext_vector_type(4)));

#define BATCH 8192
#define INDIM 2048
#define OUTD  512
#define NC    256      // 16 trees * 16 (15 nodes + 1 zero pad)
#define BM    32       // rows per block -> 256 blocks = 1/CU
#define BK    128      // GEMM1 k-chunk

__device__ __forceinline__ half8 cvt8(float4 a, float4 b) {
  half8 h;
  h[0] = (__fp16)a.x; h[1] = (__fp16)a.y; h[2] = (__fp16)a.z; h[3] = (__fp16)a.w;
  h[4] = (__fp16)b.x; h[5] = (__fp16)b.y; h[6] = (__fp16)b.z; h[7] = (__fp16)b.w;
  return h;
}

// ---- prep: WrT[c][k] fp16, c = 16t+n (n==15 zero pad), k in [0,2048) ----
__global__ void kprepW(const float* __restrict__ nw, __fp16* __restrict__ WrT) {
  int idx = blockIdx.x * 256 + threadIdx.x;      // 32768 threads: (c, k16)
  int c  = idx >> 7;
  int k0 = (idx & 127) * 16;
  int t = c >> 4, n = c & 15;
  half8 lo = {}, hi = {};
  if (n < 15) {
    const float* src = nw + (size_t)t * INDIM * 15 + n;
    #pragma unroll
    for (int j = 0; j < 8; j++) lo[j] = (__fp16)src[(size_t)(k0 + j) * 15];
    #pragma unroll
    for (int j = 0; j < 8; j++) hi[j] = (__fp16)src[(size_t)(k0 + 8 + j) * 15];
  }
  *(half8*)(WrT + (size_t)c * INDIM + k0)     = lo;
  *(half8*)(WrT + (size_t)c * INDIM + k0 + 8) = hi;
}

// ---- prep: LWrT[o][kk] fp16, kk = 16t+l ----
__global__ void kprepL(const float* __restrict__ lw, __fp16* __restrict__ LWrT) {
  int idx = blockIdx.x * 256 + threadIdx.x;      // 8192 threads: (o, t)
  int o = idx >> 4;
  int t = idx & 15;
  const float* src = lw + ((size_t)t * OUTD + o) * 16;
  half8 lo, hi;
  #pragma unroll
  for (int j = 0; j < 8; j++) lo[j] = (__fp16)src[j];
  #pragma unroll
  for (int j = 0; j < 8; j++) hi[j] = (__fp16)src[8 + j];
  *(half8*)(LWrT + (size_t)o * NC + t * 16)     = lo;
  *(half8*)(LWrT + (size_t)o * NC + t * 16 + 8) = hi;
}

// ---- fused: GEMM1 (MFMA fp16) -> gates -> leaf probs -> GEMM2 (MFMA fp16) ----
__global__ __launch_bounds__(512, 2)
void kfused(const float* __restrict__ x, const __fp16* __restrict__ WrT,
            const __fp16* __restrict__ LWrT, float* __restrict__ out) {
  // union region: Xs (2 x 32 x 128 fp16 = 16KB) during GEMM1; As (32KB f32) after
  __shared__ char   uni[BM * NC * 4];            // 32 KB
  __shared__ __fp16 Ps[BM * NC];                 // 16 KB
  __fp16* Xs = (__fp16*)uni;                     // Xs[buf][(r*BK + k') ^ ((r&7)<<3)]
  float*  As = (float*)uni;                      // As[r*NC + c]

  const int tid  = threadIdx.x;
  const int lane = tid & 63;
  const int wv   = tid >> 6;       // 0..7
  const int l15  = lane & 15;
  const int lg   = lane >> 4;      // 0..3
  const int r0   = blockIdx.x * BM;
  const int sr   = tid >> 4;       // staging row 0..31
  const int sk   = tid & 15;       // staging k-octet
  const int sOff = (sr * BK + sk * 8) ^ ((sr & 7) << 3);

  // prologue: stage X chunk 0
  {
    const float* xp = x + (size_t)(r0 + sr) * INDIM + sk * 8;
    float4 a = *(const float4*)xp;
    float4 b = *(const float4*)(xp + 4);
    *(half8*)&Xs[sOff] = cvt8(a, b);
  }

  f32x4 acc1[2][2] = {};
  const __fp16* wbase = WrT + (size_t)(32 * wv + l15) * INDIM + lg * 8;

  for (int ch = 0; ch < INDIM / BK; ++ch) {
    const int cur = ch & 1;
    // prefetch next X chunk into regs (in flight across the barrier)
    float4 a, b;
    const bool more = (ch + 1 < INDIM / BK);
    if (more) {
      const float* xp = x + (size_t)(r0 + sr) * INDIM + (ch + 1) * BK + sk * 8;
      a = *(const float4*)xp;
      b = *(const float4*)(xp + 4);
    }
    // B-frags for this chunk, direct global->reg (L2-resident WrT, block reuse == 1)
    half8 bf[2][4];
    #pragma unroll
    for (int nt = 0; nt < 2; nt++)
      #pragma unroll
      for (int ks = 0; ks < 4; ks++)
        bf[nt][ks] = *(const half8*)(wbase + (size_t)nt * 16 * INDIM + ch * BK + ks * 32);

    __syncthreads();               // Xs[cur] writes visible; prev-buf reads done

    #pragma unroll
    for (int ks = 0; ks < 4; ks++) {
      half8 af[2];
      #pragma unroll
      for (int mt = 0; mt < 2; mt++) {
        const int r = l15 + 16 * mt;
        const int e = (r * BK + ks * 32 + lg * 8) ^ ((r & 7) << 3);
        af[mt] = *(const half8*)&Xs[cur * (BM * BK) + e];
      }
      #pragma unroll
      for (int mt = 0; mt < 2; mt++)
        #pragma unroll
        for (int nt = 0; nt < 2; nt++)
          acc1[mt][nt] = __builtin_amdgcn_mfma_f32_16x16x32_f16(af[mt], bf[nt][ks], acc1[mt][nt], 0, 0, 0);
    }
    if (more)
      *(half8*)&Xs[(cur ^ 1) * (BM * BK) + sOff] = cvt8(a, b);
  }

  __syncthreads();                 // all Xs reads done before As overwrites union

  // write A tile: C layout col=lane&15, row=4*(lane>>4)+reg  [m89-verified]
  #pragma unroll
  for (int mt = 0; mt < 2; mt++)
    #pragma unroll
    for (int nt = 0; nt < 2; nt++)
      #pragma unroll
      for (int i = 0; i < 4; i++)
        As[(16 * mt + 4 * lg + i) * NC + 32 * wv + 16 * nt + l15] = acc1[mt][nt][i];
  __syncthreads();

  // gates + leaf probs: one thread per (row, tree)
  {
    const int row = tid >> 4, tr = tid & 15;
    float av[16];
    #pragma unroll
    for (int q = 0; q < 4; q++) {
      f32x4 v = *(const f32x4*)&As[row * NC + tr * 16 + 4 * q];
      av[4 * q + 0] = v[0]; av[4 * q + 1] = v[1];
      av[4 * q + 2] = v[2]; av[4 * q + 3] = v[3];
    }
    float sg[15];
    #pragma unroll
    for (int m = 0; m < 15; m++) {
      float t = fminf(fmaxf(av[m] + 0.5f, 0.f), 1.f);   // SMOOTH_STEP_PARAM = 1
      sg[m] = t * t * (3.f - 2.f * t);
    }
    float p[16];
    #pragma unroll
    for (int l = 0; l < 16; l++) {
      float pr = 1.f; int node = 0;
      #pragma unroll
      for (int L = 0; L < 4; L++) {
        int bit = (l >> (3 - L)) & 1;  // 0 = left (s), 1 = right (1-s)
        pr *= bit ? (1.f - sg[node]) : sg[node];
        node = 2 * node + 1 + bit;
      }
      p[l] = pr;
    }
    half8 h0, h1;
    #pragma unroll
    for (int j = 0; j < 8; j++) { h0[j] = (__fp16)p[j]; h1[j] = (__fp16)p[8 + j]; }
    const int base = row * NC + tr * 16;
    const int swz  = (row & 7) << 3;
    *(half8*)&Ps[(base) ^ swz]     = h0;
    *(half8*)&Ps[(base + 8) ^ swz] = h1;
  }
  __syncthreads();

  // GEMM2: out[32][512] = P[32][256] * LWrT^T ; B direct from L2 (reuse == 1)
  f32x4 acc2[2][4] = {};
  const __fp16* lbase = LWrT + (size_t)(64 * wv + l15) * NC + lg * 8;
  #pragma unroll
  for (int kc = 0; kc < 2; kc++) {
    half8 bf2[4][4];
    #pragma unroll
    for (int nt = 0; nt < 4; nt++)
      #pragma unroll
      for (int ks = 0; ks < 4; ks++)
        bf2[nt][ks] = *(const half8*)(lbase + (size_t)nt * 16 * NC + kc * 128 + ks * 32);
    #pragma unroll
    for (int ks = 0; ks < 4; ks++) {
      half8 af[2];
      #pragma unroll
      for (int mt = 0; mt < 2; mt++) {
        const int r = l15 + 16 * mt;
        const int e = (r * NC + kc * 128 + ks * 32 + lg * 8) ^ ((r & 7) << 3);
        af[mt] = *(const half8*)&Ps[e];
      }
      #pragma unroll
      for (int mt = 0; mt < 2; mt++)
        #pragma unroll
        for (int nt = 0; nt < 4; nt++)
          acc2[mt][nt] = __builtin_amdgcn_mfma_f32_16x16x32_f16(af[mt], bf2[nt][ks], acc2[mt][nt], 0, 0, 0);
    }
  }
  #pragma unroll
  for (int mt = 0; mt < 2; mt++)
    #pragma unroll
    for (int nt = 0; nt < 4; nt++)
      #pragma unroll
      for (int i = 0; i < 4; i++)
        out[(size_t)(r0 + 16 * mt + 4 * lg + i) * OUTD + 64 * wv + 16 * nt + l15] = acc2[mt][nt][i];
}

extern "C" void kernel_launch(void* const* d_in, const int* in_sizes, int n_in,
                              void* d_out, int out_size, void* d_ws, size_t ws_size,
                              hipStream_t stream) {
  const float* x  = (const float*)d_in[0];
  const float* nw = (const float*)d_in[1];
  const float* lw = (const float*)d_in[2];
  float* out = (float*)d_out;

  __fp16* WrT  = (__fp16*)d_ws;                                   // 1 MB
  __fp16* LWrT = (__fp16*)((char*)d_ws + (size_t)NC * INDIM * 2); // 256 KB

  hipLaunchKernelGGL(kprepW, dim3(128), dim3(256), 0, stream, nw, WrT);
  hipLaunchKernelGGL(kprepL, dim3(32),  dim3(256), 0, stream, lw, LWrT);
  hipLaunchKernelGGL(kfused, dim3(BATCH / BM), dim3(512), 0, stream, x, WrT, LWrT, out);
}

// Round 4
// 137.132 us; speedup vs baseline: 2.3279x; 1.0001x over previous
//
#include <hip/hip_runtime.h>
#include <cstdint>
#include <cstddef>

typedef __fp16 half8 __attribute__((ext_vector_type(8)));
typedef float  f32x4 __attribute__((ext_vector_type(4)));

#define BATCH 8192
#define INDIM 2048
#define OUTD  512
#define NC    256      // 16 trees * 16 (15 nodes + 1 zero pad)
#define BM    32       // rows per block -> 256 blocks = 1/CU
#define BK    128      // GEMM1 k-chunk
#define NCH   (INDIM / BK)   // 16 chunks

__device__ __forceinline__ half8 cvt8(float4 a, float4 b) {
  half8 h;
  h[0] = (__fp16)a.x; h[1] = (__fp16)a.y; h[2] = (__fp16)a.z; h[3] = (__fp16)a.w;
  h[4] = (__fp16)b.x; h[5] = (__fp16)b.y; h[6] = (__fp16)b.z; h[7] = (__fp16)b.w;
  return h;
}

// ---- prep: WrT[16t+n][k] fp16 (n==15 zero pad). Coalesced read + LDS transpose. ----
// 256 blocks: t = bid>>4, k0 = (bid&15)*128. Reads nw[t][k0..k0+127][0..14] linearly.
__global__ __launch_bounds__(256)
void kprepW(const float* __restrict__ nw, __fp16* __restrict__ WrT) {
  __shared__ float Ls[128][16];
  const int tid = threadIdx.x;
  const int t  = blockIdx.x >> 4;
  const int k0 = (blockIdx.x & 15) * 128;
  const float* base = nw + ((size_t)t * INDIM + k0) * 15;
  #pragma unroll
  for (int i = 0; i < 8; i++) {
    int fl = tid + 256 * i;            // 0..2047, need < 1920
    if (fl < 1920) {
      float v = base[fl];
      int kk = (int)(((unsigned)fl * 8739u) >> 17);   // fl / 15
      int n  = fl - 15 * kk;
      Ls[kk][n] = v;
    }
  }
  __syncthreads();
  const int n  = tid >> 4;             // 0..15
  const int kc = tid & 15;             // 8-wide k chunk
  half8 h = {};
  if (n < 15) {
    #pragma unroll
    for (int j = 0; j < 8; j++) h[j] = (__fp16)Ls[kc * 8 + j][n];
  }
  *(half8*)(WrT + (size_t)(16 * t + n) * INDIM + k0 + kc * 8) = h;
}

// ---- prep: LWrT[o][16t+l] fp16. Coalesced writes (16 lanes cover one full row chunk). ----
__global__ __launch_bounds__(256)
void kprepL(const float* __restrict__ lw, __fp16* __restrict__ LWrT) {
  int g = blockIdx.x * 256 + threadIdx.x;   // 8192 threads
  int o = g >> 4;
  int t = g & 15;
  const float* src = lw + ((size_t)t * OUTD + o) * 16;
  float4 a = *(const float4*)(src);
  float4 b = *(const float4*)(src + 4);
  float4 c = *(const float4*)(src + 8);
  float4 d = *(const float4*)(src + 12);
  *(half8*)(LWrT + (size_t)o * NC + t * 16)     = cvt8(a, b);
  *(half8*)(LWrT + (size_t)o * NC + t * 16 + 8) = cvt8(c, d);
}

// ---- fused: GEMM1 (MFMA fp16, pipelined) -> gates -> leaf probs -> GEMM2 ----
__global__ __launch_bounds__(512, 1)
void kfused(const float* __restrict__ x, const __fp16* __restrict__ WrT,
            const __fp16* __restrict__ LWrT, float* __restrict__ out) {
  __shared__ char   uni[BM * NC * 4];          // 32 KB: Xs dbuf (2x8KB) then As (32KB)
  __shared__ __fp16 Ps[BM * NC];               // 16 KB
  __fp16* Xs = (__fp16*)uni;                   // element (r*BK+k) ^ ((r&7)<<3), per buffer
  float*  As = (float*)uni;

  const int tid  = threadIdx.x;
  const int lane = tid & 63;
  const int wv   = tid >> 6;       // 0..7
  const int l15  = lane & 15;
  const int lg   = lane >> 4;      // 0..3
  const int r0   = blockIdx.x * BM;
  const int sr   = tid >> 4;       // staging row 0..31
  const int sk   = tid & 15;       // staging k-octet
  const int sOff = (sr * BK + sk * 8) ^ ((sr & 7) << 3);

  const float* xrow = x + (size_t)(r0 + sr) * INDIM + sk * 8;
  const __fp16* wbase = WrT + (size_t)(32 * wv + l15) * INDIM + lg * 8;

  f32x4 acc1[2][2] = {};

  // ---- pipelined GEMM1: B reg-dbuf (1 chunk ahead), X 2-deep prefetch ----
  half8 bfA[2][4], bfB[2][4];
  float4 xN0, xN1, xM0, xM1;

  #define LDB(dst, ch)                                                          \
    _Pragma("unroll") for (int nt = 0; nt < 2; nt++)                            \
    _Pragma("unroll") for (int ks = 0; ks < 4; ks++)                            \
      dst[nt][ks] = *(const half8*)(wbase + (size_t)nt * 16 * INDIM + (ch) * BK + ks * 32);

  #define LDX(d0, d1, ch)                                                       \
    d0 = *(const float4*)(xrow + (ch) * BK);                                    \
    d1 = *(const float4*)(xrow + (ch) * BK + 4);

  #define STX(buf, d0, d1)                                                      \
    *(half8*)&Xs[(buf) * (BM * BK) + sOff] = cvt8(d0, d1);

  #define COMPUTE(buf, bf)                                                      \
    _Pragma("unroll") for (int ks = 0; ks < 4; ks++) {                          \
      half8 af[2];                                                              \
      _Pragma("unroll") for (int mt = 0; mt < 2; mt++) {                        \
        const int r = l15 + 16 * mt;                                            \
        const int e = (r * BK + ks * 32 + lg * 8) ^ ((r & 7) << 3);             \
        af[mt] = *(const half8*)&Xs[(buf) * (BM * BK) + e];                     \
      }                                                                         \
      _Pragma("unroll") for (int mt = 0; mt < 2; mt++)                          \
      _Pragma("unroll") for (int nt = 0; nt < 2; nt++)                          \
        acc1[mt][nt] = __builtin_amdgcn_mfma_f32_16x16x32_f16(af[mt], bf[nt][ks], acc1[mt][nt], 0, 0, 0); \
    }

  // prologue: chunk 0 staged, X(1) in flight, B(0) in flight
  { float4 a, b; LDX(a, b, 0); STX(0, a, b); }
  LDX(xN0, xN1, 1);
  LDB(bfA, 0);

  #pragma unroll 1
  for (int ch = 0; ch < NCH; ch += 2) {
    // even: compute buf0/bfA, write buf1 with X(ch+1), prefetch B(ch+1), X(ch+2)
    LDB(bfB, ch + 1);
    if (ch + 2 < NCH) { LDX(xM0, xM1, ch + 2); }
    __syncthreads();
    STX(1, xN0, xN1);
    COMPUTE(0, bfA);
    // odd: compute buf1/bfB, write buf0 with X(ch+2), prefetch B(ch+2), X(ch+3)
    if (ch + 2 < NCH) { LDB(bfA, ch + 2); }
    if (ch + 3 < NCH) { LDX(xN0, xN1, ch + 3); }
    __syncthreads();
    if (ch + 2 < NCH) { STX(0, xM0, xM1); }
    COMPUTE(1, bfB);
  }

  __syncthreads();                 // all Xs reads done before As overwrites union

  // write A tile: C layout col=lane&15, row=4*(lane>>4)+reg  [m89-verified]
  #pragma unroll
  for (int mt = 0; mt < 2; mt++)
    #pragma unroll
    for (int nt = 0; nt < 2; nt++)
      #pragma unroll
      for (int i = 0; i < 4; i++)
        As[(16 * mt + 4 * lg + i) * NC + 32 * wv + 16 * nt + l15] = acc1[mt][nt][i];
  __syncthreads();

  // gates + leaf probs: one thread per (row, tree)
  {
    const int row = tid >> 4, tr = tid & 15;
    float av[16];
    #pragma unroll
    for (int q = 0; q < 4; q++) {
      f32x4 v = *(const f32x4*)&As[row * NC + tr * 16 + 4 * q];
      av[4 * q + 0] = v[0]; av[4 * q + 1] = v[1];
      av[4 * q + 2] = v[2]; av[4 * q + 3] = v[3];
    }
    float sg[15];
    #pragma unroll
    for (int m = 0; m < 15; m++) {
      float t = fminf(fmaxf(av[m] + 0.5f, 0.f), 1.f);   // SMOOTH_STEP_PARAM = 1
      sg[m] = t * t * (3.f - 2.f * t);
    }
    float p[16];
    #pragma unroll
    for (int l = 0; l < 16; l++) {
      float pr = 1.f; int node = 0;
      #pragma unroll
      for (int L = 0; L < 4; L++) {
        int bit = (l >> (3 - L)) & 1;  // 0 = left (s), 1 = right (1-s)
        pr *= bit ? (1.f - sg[node]) : sg[node];
        node = 2 * node + 1 + bit;
      }
      p[l] = pr;
    }
    half8 h0, h1;
    #pragma unroll
    for (int j = 0; j < 8; j++) { h0[j] = (__fp16)p[j]; h1[j] = (__fp16)p[8 + j]; }
    const int base = row * NC + tr * 16;
    const int swz  = (row & 7) << 3;
    *(half8*)&Ps[(base) ^ swz]     = h0;
    *(half8*)&Ps[(base + 8) ^ swz] = h1;
  }
  __syncthreads();

  // GEMM2: out[32][512] = P[32][256] * LWrT^T ; B direct from L2 (reuse == 1)
  f32x4 acc2[2][4] = {};
  const __fp16* lbase = LWrT + (size_t)(64 * wv + l15) * NC + lg * 8;
  #pragma unroll
  for (int kc = 0; kc < 2; kc++) {
    half8 bf2[4][4];
    #pragma unroll
    for (int nt = 0; nt < 4; nt++)
      #pragma unroll
      for (int ks = 0; ks < 4; ks++)
        bf2[nt][ks] = *(const half8*)(lbase + (size_t)nt * 16 * NC + kc * 128 + ks * 32);
    #pragma unroll
    for (int ks = 0; ks < 4; ks++) {
      half8 af[2];
      #pragma unroll
      for (int mt = 0; mt < 2; mt++) {
        const int r = l15 + 16 * mt;
        const int e = (r * NC + kc * 128 + ks * 32 + lg * 8) ^ ((r & 7) << 3);
        af[mt] = *(const half8*)&Ps[e];
      }
      #pragma unroll
      for (int mt = 0; mt < 2; mt++)
        #pragma unroll
        for (int nt = 0; nt < 4; nt++)
          acc2[mt][nt] = __builtin_amdgcn_mfma_f32_16x16x32_f16(af[mt], bf2[nt][ks], acc2[mt][nt], 0, 0, 0);
    }
  }
  #pragma unroll
  for (int mt = 0; mt < 2; mt++)
    #pragma unroll
    for (int nt = 0; nt < 4; nt++)
      #pragma unroll
      for (int i = 0; i < 4; i++)
        out[(size_t)(r0 + 16 * mt + 4 * lg + i) * OUTD + 64 * wv + 16 * nt + l15] = acc2[mt][nt][i];
}

extern "C" void kernel_launch(void* const* d_in, const int* in_sizes, int n_in,
                              void* d_out, int out_size, void* d_ws, size_t ws_size,
                              hipStream_t stream) {
  const float* x  = (const float*)d_in[0];
  const float* nw = (const float*)d_in[1];
  const float* lw = (const float*)d_in[2];
  float* out = (float*)d_out;

  __fp16* WrT  = (__fp16*)d_ws;                                   // 1 MB
  __fp16* LWrT = (__fp16*)((char*)d_ws + (size_t)NC * INDIM * 2); // 256 KB

  hipLaunchKernelGGL(kprepW, dim3(256), dim3(256), 0, stream, nw, WrT);
  hipLaunchKernelGGL(kprepL, dim3(32),  dim3(256), 0, stream, lw, LWrT);
  hipLaunchKernelGGL(kfused, dim3(BATCH / BM), dim3(512), 0, stream, x, WrT, LWrT, out);
}